// Round 4
// baseline (2300.762 us; speedup 1.0000x reference)
//
#include <hip/hip_runtime.h>
#include <hip/hip_bf16.h>

typedef __bf16 bf16;
typedef __bf16 bf16x8 __attribute__((ext_vector_type(8)));
typedef float f32x4 __attribute__((ext_vector_type(4)));

#define B_SZ 2048
#define L_SZ 200
#define D_SZ 256
#define MT 48            // rows per l-tile (3 m-tiles of 16)
#define NTILE 5          // ceil(200/48)
#define AST 264          // LDS activation row stride in bf16

// load 8 consecutive fp32, convert to a bf16x8 MFMA fragment
__device__ __forceinline__ bf16x8 cvt8(const float* __restrict__ f) {
    float4 a = *(const float4*)f;
    float4 b = *(const float4*)(f + 4);
    bf16x8 r;
    r[0] = (bf16)a.x; r[1] = (bf16)a.y; r[2] = (bf16)a.z; r[3] = (bf16)a.w;
    r[4] = (bf16)b.x; r[5] = (bf16)b.y; r[6] = (bf16)b.z; r[7] = (bf16)b.w;
    return r;
}

// stage 48 gathered fp32 rows (256 elems each) into LDS as bf16
__device__ __forceinline__ void gather_half(const int* __restrict__ idxp,
                                            const float* __restrict__ table,
                                            bf16* __restrict__ buf, int l0, int t) {
#pragma unroll
    for (int it = 0; it < 6; ++it) {
        int g = it * 256 + t;
        int r = g >> 5;           // 0..47
        int c = g & 31;           // 8-elem chunk within row
        int l = l0 + r;
        int li = l < L_SZ ? l : (L_SZ - 1);
        long row = idxp[li];
        bf16x8 v = cvt8(table + row * D_SZ + c * 8);
        *(bf16x8*)(buf + r * AST + c * 8) = v;
    }
}

// one GEMM pass: A [48 x 256] bf16 from LDS; B fragment = W[n0+l16][koff+kt*32+quad*8 ..+7]
// (W row-major [N,K] fp32, converted inline; MFMA computes D[m][n] = sum_k A[m,k]*W[n,k])
__device__ __forceinline__ void run_gemm(const bf16* __restrict__ abase,
                                         const float* __restrict__ W, int ldw, int koff,
                                         int wave, int l16, int quad,
                                         f32x4 acc[3][4]) {
#pragma unroll
    for (int kt = 0; kt < 8; ++kt) {
        bf16x8 a[3];
#pragma unroll
        for (int mt = 0; mt < 3; ++mt)
            a[mt] = *(const bf16x8*)(abase + (mt * 16 + l16) * AST + kt * 32 + quad * 8);
#pragma unroll
        for (int nt = 0; nt < 4; ++nt) {
            bf16x8 bv = cvt8(W + (long)((wave * 4 + nt) * 16 + l16) * ldw
                               + koff + kt * 32 + quad * 8);
#pragma unroll
            for (int mt = 0; mt < 3; ++mt)
                acc[mt][nt] = __builtin_amdgcn_mfma_f32_16x16x32_bf16(a[mt], bv, acc[mt][nt], 0, 0, 0);
        }
    }
}

__device__ __forceinline__ void zero_acc(f32x4 acc[3][4]) {
    f32x4 z = {0.f, 0.f, 0.f, 0.f};
#pragma unroll
    for (int mt = 0; mt < 3; ++mt)
#pragma unroll
        for (int nt = 0; nt < 4; ++nt) acc[mt][nt] = z;
}

// C-layout (col=lane&15, row=quad*4+reg) -> relu(acc+bias) -> LDS [48][AST] bf16
__device__ __forceinline__ void store_act(bf16* __restrict__ buf, f32x4 acc[3][4],
                                          const float* bias, int wave, int l16, int quad) {
#pragma unroll
    for (int mt = 0; mt < 3; ++mt)
#pragma unroll
        for (int nt = 0; nt < 4; ++nt) {
            int col = (wave * 4 + nt) * 16 + l16;
#pragma unroll
            for (int r = 0; r < 4; ++r) {
                int row = mt * 16 + quad * 4 + r;
                float v = acc[mt][nt][r] + bias[nt];
                v = v > 0.f ? v : 0.f;
                buf[row * AST + col] = (bf16)v;
            }
        }
}

__global__ void ua_agg_kernel(const int* __restrict__ nodes,
                              const int* __restrict__ hua,
                              const int* __restrict__ hr,
                              const float* __restrict__ u2e,
                              const float* __restrict__ attr,
                              const float* __restrict__ r2e,
                              const float* __restrict__ w1,
                              const float* __restrict__ b1w,
                              const float* __restrict__ w2,
                              const float* __restrict__ b2w,
                              const float* __restrict__ att1w,
                              const float* __restrict__ a1b,
                              const float* __restrict__ att2w,
                              const float* __restrict__ a2b,
                              const float* __restrict__ att3w,
                              const float* __restrict__ a3bp,
                              float* __restrict__ out) {
    __shared__ __align__(16) bf16 abuf[MT * AST];   // union: A-half / x / h1
    __shared__ __align__(16) bf16 obuf[MT * AST];   // o (layer-2 output), kept for reduce
    __shared__ float h1pre[D_SZ];
    __shared__ float scratch[288];                  // ua_rep(256) | score_part(192)+score_row(48)+wrow(48)

    const int b = blockIdx.x;
    const int t = threadIdx.x;
    const int wave = t >> 6;
    const int l16 = t & 15;
    const int quad = (t & 63) >> 4;

    // ---- h1pre[n] = att1_b[n] + sum_k ua_rep[k] * att1_w[n][256+k]  (fp32, once per block) ----
    {
        int node = nodes[b];
        scratch[t] = u2e[(long)node * D_SZ + t];
        __syncthreads();
        float a = a1b[t];
        const float* wr = att1w + (long)t * 512 + 256;
#pragma unroll
        for (int k = 0; k < 256; k += 4) {
            float4 wv = *(const float4*)(wr + k);
            a += scratch[k] * wv.x + scratch[k + 1] * wv.y +
                 scratch[k + 2] * wv.z + scratch[k + 3] * wv.w;
        }
        h1pre[t] = a;
        __syncthreads();
    }

    // per-lane column biases (col = (wave*4+nt)*16 + l16)
    float bias1[4], bias2[4], bias3[4], bias4[4], a3[4];
#pragma unroll
    for (int nt = 0; nt < 4; ++nt) {
        int col = (wave * 4 + nt) * 16 + l16;
        bias1[nt] = b1w[col];
        bias2[nt] = b2w[col];
        bias3[nt] = h1pre[col];      // includes att1_b
        bias4[nt] = a2b[col];
        a3[nt] = att3w[col];
    }
    const float a3bias = a3bp[0];

    const int* huab = hua + (long)b * L_SZ;
    const int* hrb = hr + (long)b * L_SZ;

    float accv = 0.f, srun = 0.f, mrun = -INFINITY;
    float* score_part = scratch;        // [4][48]
    float* score_row = scratch + 192;   // [48]
    float* wrow = scratch + 240;        // [48]

    for (int tile = 0; tile < NTILE; ++tile) {
        const int l0 = tile * MT;
        f32x4 acc[3][4];
        zero_acc(acc);

        // ---- layer 1 (K=512: e_ua half then e_r half) ----
        gather_half(huab, attr, abuf, l0, t);
        __syncthreads();
        run_gemm(abuf, w1, 512, 0, wave, l16, quad, acc);
        __syncthreads();
        gather_half(hrb, r2e, abuf, l0, t);
        __syncthreads();
        run_gemm(abuf, w1, 512, 256, wave, l16, quad, acc);
        __syncthreads();
        store_act(abuf, acc, bias1, wave, l16, quad);   // x -> abuf
        __syncthreads();

        // ---- layer 2: o = relu(W2 x + b2) ----
        zero_acc(acc);
        run_gemm(abuf, w2, 256, 0, wave, l16, quad, acc);
        store_act(obuf, acc, bias2, wave, l16, quad);   // o -> obuf
        __syncthreads();

        // ---- layer 3: h1 = relu(att1[:, :256] o + h1pre) ----
        zero_acc(acc);
        run_gemm(obuf, att1w, 512, 0, wave, l16, quad, acc);
        store_act(abuf, acc, bias3, wave, l16, quad);   // h1 -> abuf
        __syncthreads();

        // ---- layer 4 + score ----
        zero_acc(acc);
        run_gemm(abuf, att2w, 256, 0, wave, l16, quad, acc);

        float p[3][4];
#pragma unroll
        for (int mt = 0; mt < 3; ++mt)
#pragma unroll
            for (int r = 0; r < 4; ++r) {
                float s = 0.f;
#pragma unroll
                for (int nt = 0; nt < 4; ++nt) {
                    float h = acc[mt][nt][r] + bias4[nt];
                    h = h > 0.f ? h : 0.f;
                    s += h * a3[nt];
                }
                p[mt][r] = s;
            }
        // sum over the 16 l16-lanes within each quad group (width-16 xor shuffle)
#pragma unroll
        for (int off = 1; off < 16; off <<= 1)
#pragma unroll
            for (int mt = 0; mt < 3; ++mt)
#pragma unroll
                for (int r = 0; r < 4; ++r) p[mt][r] += __shfl_xor(p[mt][r], off, 16);
        if (l16 == 0) {
#pragma unroll
            for (int mt = 0; mt < 3; ++mt)
#pragma unroll
                for (int r = 0; r < 4; ++r)
                    score_part[wave * 48 + mt * 16 + quad * 4 + r] = p[mt][r];
        }
        __syncthreads();
        if (t < MT) {
            float s = score_part[t] + score_part[48 + t] + score_part[96 + t] +
                      score_part[144 + t] + a3bias;
            score_row[t] = (l0 + t < L_SZ) ? s : -INFINITY;
        }
        __syncthreads();

        // ---- online softmax + weighted accumulate (thread t owns output column t) ----
        float tm = -INFINITY;
        for (int r = 0; r < MT; ++r) tm = fmaxf(tm, score_row[r]);
        float nm = fmaxf(mrun, tm);
        float factor = __expf(mrun - nm);   // 0 on first tile (mrun=-inf)
        if (t < MT) wrow[t] = __expf(score_row[t] - nm);  // 0 for masked rows
        __syncthreads();
        float wsum = 0.f, av = 0.f;
#pragma unroll 8
        for (int r = 0; r < MT; ++r) {
            float w = wrow[r];
            wsum += w;
            av += w * (float)obuf[r * AST + t];
        }
        accv = accv * factor + av;
        srun = srun * factor + wsum;
        mrun = nm;
        __syncthreads();
    }

    out[(long)b * D_SZ + t] = accv / srun;
}

extern "C" void kernel_launch(void* const* d_in, const int* in_sizes, int n_in,
                              void* d_out, int out_size, void* d_ws, size_t ws_size,
                              hipStream_t stream) {
    const int* nodes = (const int*)d_in[0];
    const int* hua = (const int*)d_in[1];
    const int* hr = (const int*)d_in[2];
    // d_in[3] history_uat unused by the reference
    const float* u2e = (const float*)d_in[4];
    const float* attr = (const float*)d_in[5];
    const float* r2e = (const float*)d_in[6];
    const float* w1 = (const float*)d_in[7];
    const float* b1 = (const float*)d_in[8];
    const float* w2 = (const float*)d_in[9];
    const float* b2 = (const float*)d_in[10];
    const float* a1w = (const float*)d_in[11];
    const float* a1b = (const float*)d_in[12];
    const float* a2w = (const float*)d_in[13];
    const float* a2b = (const float*)d_in[14];
    const float* a3w = (const float*)d_in[15];
    const float* a3b = (const float*)d_in[16];

    ua_agg_kernel<<<B_SZ, 256, 0, stream>>>(nodes, hua, hr, u2e, attr, r2e,
                                            w1, b1, w2, b2, a1w, a1b, a2w, a2b,
                                            a3w, a3b, (float*)d_out);
}

// Round 5
// 2040.152 us; speedup vs baseline: 1.1277x; 1.1277x over previous
//
#include <hip/hip_runtime.h>
#include <hip/hip_bf16.h>

typedef __bf16 bf16;
typedef __bf16 bf16x8 __attribute__((ext_vector_type(8)));
typedef float f32x4 __attribute__((ext_vector_type(4)));

#define B_SZ 2048
#define L_SZ 200
#define D_SZ 256
#define MT 48            // rows per l-tile (3 m-tiles of 16)
#define NTILE 5          // ceil(200/48)
#define AST 264          // LDS activation row stride in bf16

// workspace offsets in bf16 elements (pre-swizzled bf16 weight fragments)
#define W1F_OFF 0        // w1   256x512 -> 131072
#define W2F_OFF 131072   // w2   256x256 -> 65536
#define A1F_OFF 196608   // att1[:, 0:256] -> 65536
#define A2F_OFF 262144   // att2 256x256 -> 65536

// Pre-swizzle fp32 weights into bf16 MFMA B-fragment order:
// dst[((nt*KT + kt)*64 + lane)*8 + j] = (bf16)W[nt*16 + (lane&15)][koff + kt*32 + (lane>>4)*8 + j]
__global__ void swizzle_kernel(const float* __restrict__ W, bf16* __restrict__ dst,
                               int KT, int ldw, int koff, int total) {
    int g = blockIdx.x * blockDim.x + threadIdx.x;
    if (g >= total) return;
    int lane = g & 63;
    int kt = (g >> 6) % KT;
    int nt = g / (64 * KT);
    int n = nt * 16 + (lane & 15);
    int k = kt * 32 + (lane >> 4) * 8;
    const float* src = W + (long)n * ldw + koff + k;
    float4 a = *(const float4*)src;
    float4 b = *(const float4*)(src + 4);
    bf16x8 v;
    v[0] = (bf16)a.x; v[1] = (bf16)a.y; v[2] = (bf16)a.z; v[3] = (bf16)a.w;
    v[4] = (bf16)b.x; v[5] = (bf16)b.y; v[6] = (bf16)b.z; v[7] = (bf16)b.w;
    *(bf16x8*)(dst + (long)g * 8) = v;
}

// stage 48 gathered fp32 rows (256 elems each) into LDS as bf16
__device__ __forceinline__ void gather_half(const int* __restrict__ idxp,
                                            const float* __restrict__ table,
                                            bf16* __restrict__ buf, int l0, int t) {
#pragma unroll
    for (int it = 0; it < 6; ++it) {
        int g = it * 256 + t;
        int r = g >> 5;           // 0..47
        int c = g & 31;           // 8-elem chunk within row
        int l = l0 + r;
        int li = l < L_SZ ? l : (L_SZ - 1);
        long row = idxp[li];
        const float* f = table + row * D_SZ + c * 8;
        float4 a = *(const float4*)f;
        float4 b2 = *(const float4*)(f + 4);
        bf16x8 v;
        v[0] = (bf16)a.x; v[1] = (bf16)a.y; v[2] = (bf16)a.z; v[3] = (bf16)a.w;
        v[4] = (bf16)b2.x; v[5] = (bf16)b2.y; v[6] = (bf16)b2.z; v[7] = (bf16)b2.w;
        *(bf16x8*)(buf + r * AST + c * 8) = v;
    }
}

// GEMM pass over pre-swizzled fragments: fragment (ntg, kt) lives at
// wfrag + ((ntg*KTOT + kt)*64 + lane)*8, a single coalesced dwordx4 per lane.
// Double-buffered: next kt's 4 fragments load while current kt's 12 MFMAs issue.
template <int KTOT>
__device__ __forceinline__ void run_gemm_f(const bf16* __restrict__ abase,
                                           const bf16* __restrict__ wfrag,
                                           int koff_t, int wave, int lane,
                                           int l16, int quad, f32x4 acc[3][4]) {
    const bf16* wbase = wfrag + ((long)(wave * 4) * KTOT + koff_t) * 512 + lane * 8;
    bf16x8 bcur[4], bnxt[4];
#pragma unroll
    for (int nt = 0; nt < 4; ++nt)
        bcur[nt] = *(const bf16x8*)(wbase + (long)nt * KTOT * 512);
#pragma unroll
    for (int kt = 0; kt < 8; ++kt) {
        if (kt < 7) {
#pragma unroll
            for (int nt = 0; nt < 4; ++nt)
                bnxt[nt] = *(const bf16x8*)(wbase + ((long)nt * KTOT + kt + 1) * 512);
        }
        bf16x8 a[3];
#pragma unroll
        for (int mt = 0; mt < 3; ++mt)
            a[mt] = *(const bf16x8*)(abase + (mt * 16 + l16) * AST + kt * 32 + quad * 8);
#pragma unroll
        for (int nt = 0; nt < 4; ++nt)
#pragma unroll
            for (int mt = 0; mt < 3; ++mt)
                acc[mt][nt] = __builtin_amdgcn_mfma_f32_16x16x32_bf16(a[mt], bcur[nt], acc[mt][nt], 0, 0, 0);
#pragma unroll
        for (int nt = 0; nt < 4; ++nt) bcur[nt] = bnxt[nt];
    }
}

__device__ __forceinline__ void zero_acc(f32x4 acc[3][4]) {
    f32x4 z = {0.f, 0.f, 0.f, 0.f};
#pragma unroll
    for (int mt = 0; mt < 3; ++mt)
#pragma unroll
        for (int nt = 0; nt < 4; ++nt) acc[mt][nt] = z;
}

// C-layout (col=lane&15, row=quad*4+reg) -> relu(acc+bias) -> LDS [48][AST] bf16
__device__ __forceinline__ void store_act(bf16* __restrict__ buf, f32x4 acc[3][4],
                                          const float* bias, int wave, int l16, int quad) {
#pragma unroll
    for (int mt = 0; mt < 3; ++mt)
#pragma unroll
        for (int nt = 0; nt < 4; ++nt) {
            int col = (wave * 4 + nt) * 16 + l16;
#pragma unroll
            for (int r = 0; r < 4; ++r) {
                int row = mt * 16 + quad * 4 + r;
                float v = acc[mt][nt][r] + bias[nt];
                v = v > 0.f ? v : 0.f;
                buf[row * AST + col] = (bf16)v;
            }
        }
}

__launch_bounds__(256, 3)
__global__ void ua_agg_kernel(const int* __restrict__ nodes,
                              const int* __restrict__ hua,
                              const int* __restrict__ hr,
                              const float* __restrict__ u2e,
                              const float* __restrict__ attr,
                              const float* __restrict__ r2e,
                              const bf16* __restrict__ wf,       // swizzled weights in ws
                              const float* __restrict__ b1w,
                              const float* __restrict__ b2w,
                              const float* __restrict__ att1w,   // fp32, for h1pre only
                              const float* __restrict__ a1b,
                              const float* __restrict__ a2b,
                              const float* __restrict__ att3w,
                              const float* __restrict__ a3bp,
                              float* __restrict__ out) {
    __shared__ __align__(16) bf16 abuf[MT * AST];   // union: A-half / x / h1
    __shared__ __align__(16) bf16 obuf[MT * AST];   // o (layer-2 output), kept for reduce
    __shared__ float h1pre[D_SZ];
    __shared__ float scratch[288];                  // ua_rep(256) | score_part(192)+score_row(48)+wrow(48)

    const int b = blockIdx.x;
    const int t = threadIdx.x;
    const int wave = t >> 6;
    const int lane = t & 63;
    const int l16 = t & 15;
    const int quad = (t & 63) >> 4;

    // ---- h1pre[n] = att1_b[n] + sum_k ua_rep[k] * att1_w[n][256+k]  (fp32, once per block) ----
    {
        int node = nodes[b];
        scratch[t] = u2e[(long)node * D_SZ + t];
        __syncthreads();
        float a = a1b[t];
        const float* wr = att1w + (long)t * 512 + 256;
#pragma unroll
        for (int k = 0; k < 256; k += 4) {
            float4 wv = *(const float4*)(wr + k);
            a += scratch[k] * wv.x + scratch[k + 1] * wv.y +
                 scratch[k + 2] * wv.z + scratch[k + 3] * wv.w;
        }
        h1pre[t] = a;
        __syncthreads();
    }

    // per-lane column biases (col = (wave*4+nt)*16 + l16)
    float bias1[4], bias2[4], bias3[4], bias4[4], a3[4];
#pragma unroll
    for (int nt = 0; nt < 4; ++nt) {
        int col = (wave * 4 + nt) * 16 + l16;
        bias1[nt] = b1w[col];
        bias2[nt] = b2w[col];
        bias3[nt] = h1pre[col];      // includes att1_b
        bias4[nt] = a2b[col];
        a3[nt] = att3w[col];
    }
    const float a3bias = a3bp[0];

    const int* huab = hua + (long)b * L_SZ;
    const int* hrb = hr + (long)b * L_SZ;

    float accv = 0.f, srun = 0.f, mrun = -INFINITY;
    float* score_part = scratch;        // [4][48]
    float* score_row = scratch + 192;   // [48]
    float* wrow = scratch + 240;        // [48]

    for (int tile = 0; tile < NTILE; ++tile) {
        const int l0 = tile * MT;
        f32x4 acc[3][4];
        zero_acc(acc);

        // ---- layer 1 (K=512: e_ua half then e_r half) ----
        gather_half(huab, attr, abuf, l0, t);
        __syncthreads();
        run_gemm_f<16>(abuf, wf + W1F_OFF, 0, wave, lane, l16, quad, acc);
        __syncthreads();
        gather_half(hrb, r2e, abuf, l0, t);
        __syncthreads();
        run_gemm_f<16>(abuf, wf + W1F_OFF, 8, wave, lane, l16, quad, acc);
        __syncthreads();
        store_act(abuf, acc, bias1, wave, l16, quad);   // x -> abuf
        __syncthreads();

        // ---- layer 2: o = relu(W2 x + b2) ----
        zero_acc(acc);
        run_gemm_f<8>(abuf, wf + W2F_OFF, 0, wave, lane, l16, quad, acc);
        store_act(obuf, acc, bias2, wave, l16, quad);   // o -> obuf
        __syncthreads();

        // ---- layer 3: h1 = relu(att1[:, :256] o + h1pre) ----
        zero_acc(acc);
        run_gemm_f<8>(obuf, wf + A1F_OFF, 0, wave, lane, l16, quad, acc);
        store_act(abuf, acc, bias3, wave, l16, quad);   // h1 -> abuf
        __syncthreads();

        // ---- layer 4 + score ----
        zero_acc(acc);
        run_gemm_f<8>(abuf, wf + A2F_OFF, 0, wave, lane, l16, quad, acc);

        float p[3][4];
#pragma unroll
        for (int mt = 0; mt < 3; ++mt)
#pragma unroll
            for (int r = 0; r < 4; ++r) {
                float s = 0.f;
#pragma unroll
                for (int nt = 0; nt < 4; ++nt) {
                    float h = acc[mt][nt][r] + bias4[nt];
                    h = h > 0.f ? h : 0.f;
                    s += h * a3[nt];
                }
                p[mt][r] = s;
            }
        // sum over the 16 l16-lanes within each quad group (width-16 xor shuffle)
#pragma unroll
        for (int off = 1; off < 16; off <<= 1)
#pragma unroll
            for (int mt = 0; mt < 3; ++mt)
#pragma unroll
                for (int r = 0; r < 4; ++r) p[mt][r] += __shfl_xor(p[mt][r], off, 16);
        if (l16 == 0) {
#pragma unroll
            for (int mt = 0; mt < 3; ++mt)
#pragma unroll
                for (int r = 0; r < 4; ++r)
                    score_part[wave * 48 + mt * 16 + quad * 4 + r] = p[mt][r];
        }
        __syncthreads();
        if (t < MT) {
            float s = score_part[t] + score_part[48 + t] + score_part[96 + t] +
                      score_part[144 + t] + a3bias;
            score_row[t] = (l0 + t < L_SZ) ? s : -INFINITY;
        }
        __syncthreads();

        // ---- online softmax + weighted accumulate (thread t owns output column t) ----
        float tm = -INFINITY;
        for (int r = 0; r < MT; ++r) tm = fmaxf(tm, score_row[r]);
        float nm = fmaxf(mrun, tm);
        float factor = __expf(mrun - nm);   // 0 on first tile (mrun=-inf)
        if (t < MT) wrow[t] = __expf(score_row[t] - nm);  // 0 for masked rows
        __syncthreads();
        float wsum = 0.f, av = 0.f;
#pragma unroll 8
        for (int r = 0; r < MT; ++r) {
            float w = wrow[r];
            wsum += w;
            av += w * (float)obuf[r * AST + t];
        }
        accv = accv * factor + av;
        srun = srun * factor + wsum;
        mrun = nm;
        __syncthreads();
    }

    out[(long)b * D_SZ + t] = accv / srun;
}

extern "C" void kernel_launch(void* const* d_in, const int* in_sizes, int n_in,
                              void* d_out, int out_size, void* d_ws, size_t ws_size,
                              hipStream_t stream) {
    const int* nodes = (const int*)d_in[0];
    const int* hua = (const int*)d_in[1];
    const int* hr = (const int*)d_in[2];
    // d_in[3] history_uat unused by the reference
    const float* u2e = (const float*)d_in[4];
    const float* attr = (const float*)d_in[5];
    const float* r2e = (const float*)d_in[6];
    const float* w1 = (const float*)d_in[7];
    const float* b1 = (const float*)d_in[8];
    const float* w2 = (const float*)d_in[9];
    const float* b2 = (const float*)d_in[10];
    const float* a1w = (const float*)d_in[11];
    const float* a1b = (const float*)d_in[12];
    const float* a2w = (const float*)d_in[13];
    const float* a2b = (const float*)d_in[14];
    const float* a3w = (const float*)d_in[15];
    const float* a3b = (const float*)d_in[16];
    bf16* wsb = (bf16*)d_ws;

    // one-time (per launch, idempotent) fp32 -> bf16 fragment swizzle of all weights
    swizzle_kernel<<<64, 256, 0, stream>>>(w1, wsb + W1F_OFF, 16, 512, 0, 16384);
    swizzle_kernel<<<32, 256, 0, stream>>>(w2, wsb + W2F_OFF, 8, 256, 0, 8192);
    swizzle_kernel<<<32, 256, 0, stream>>>(a1w, wsb + A1F_OFF, 8, 512, 0, 8192);
    swizzle_kernel<<<32, 256, 0, stream>>>(a2w, wsb + A2F_OFF, 8, 256, 0, 8192);

    ua_agg_kernel<<<B_SZ, 256, 0, stream>>>(nodes, hua, hr, u2e, attr, r2e,
                                            wsb, b1, b2, a1w, a1b, a2b,
                                            a3w, a3b, (float*)d_out);
}